// Round 7
// baseline (580.075 us; speedup 1.0000x reference)
//
#include <hip/hip_runtime.h>
#include <cstdint>
#include <cstddef>

typedef __bf16 bf16_t;
typedef __bf16 bf16x4 __attribute__((ext_vector_type(4)));
typedef __bf16 bf16x8 __attribute__((ext_vector_type(8)));
typedef float floatx4 __attribute__((ext_vector_type(4)));

#define B_ 4
#define S_ 2048
#define E_ 1024
#define SV_ 50
#define SVP_ 64
#define BSE_ ((long)B_ * S_ * E_)

__device__ __forceinline__ void async_copy16(const bf16_t* g, bf16_t* l) {
  __builtin_amdgcn_global_load_lds(
      (const __attribute__((address_space(1))) void*)g,
      (__attribute__((address_space(3))) void*)l, 16, 0, 0);
}

// ---------------- tanh of Q and K (concat), float4 vectorized ----------------
__global__ __launch_bounds__(256) void tanh2_k(const float* __restrict__ Q,
                                               const float* __restrict__ Kin,
                                               bf16_t* __restrict__ out) {
  long i4 = ((long)blockIdx.x * 256 + threadIdx.x) * 4;
  const long n = (long)B_ * S_ * E_;
  const float* src = (i4 < n) ? (Q + i4) : (Kin + (i4 - n));
  float4 x = *(const float4*)src;
  bf16x4 o;
  o[0] = (bf16_t)tanhf(x.x);
  o[1] = (bf16_t)tanhf(x.y);
  o[2] = (bf16_t)tanhf(x.z);
  o[3] = (bf16_t)tanhf(x.w);
  *(bf16x4*)&out[i4] = o;
}

// V [B,50,1024] -> tanh, padded to [B,64,1024] with zero rows
__global__ __launch_bounds__(256) void tanh_vpad_k(const float* __restrict__ V,
                                                   bf16_t* __restrict__ out) {
  int i = blockIdx.x * 256 + threadIdx.x;  // covers B*64*1024
  int e = i & 1023, r = (i >> 10) & 63, b = i >> 16;
  float v = 0.f;
  if (r < SV_) v = tanhf(V[((long)(b * SV_ + r) << 10) + e]);
  out[i] = (bf16_t)v;
}

// ------- W [K,N] fp32 -> Wt [N,Kp] bf16 (zero-pad k>=K); 3-way z select -------
__global__ __launch_bounds__(256) void transp_cast3_k(const float* __restrict__ W0,
                                                      const float* __restrict__ W1,
                                                      const float* __restrict__ W2,
                                                      bf16_t* __restrict__ out,
                                                      int K, int N, int Kp) {
  __shared__ float tile[32][33];
  const float* W = (blockIdx.z == 0) ? W0 : (blockIdx.z == 1) ? W1 : W2;
  bf16_t* o = out + (long)blockIdx.z * N * Kp;
  int k0 = blockIdx.y * 32, n0 = blockIdx.x * 32;
  int tx = threadIdx.x, ty = threadIdx.y;  // block (32,8)
#pragma unroll
  for (int s2 = 0; s2 < 4; ++s2) {
    int kk = ty + s2 * 8;
    float v = 0.f;
    if (k0 + kk < K && n0 + tx < N) v = W[(long)(k0 + kk) * N + n0 + tx];
    tile[kk][tx] = v;
  }
  __syncthreads();
#pragma unroll
  for (int s2 = 0; s2 < 4; ++s2) {
    int nn = ty + s2 * 8;
    if (n0 + nn < N && k0 + tx < Kp)
      o[(long)(n0 + nn) * Kp + k0 + tx] = (bf16_t)tile[tx][nn];
  }
}

// ------ strided bf16 transpose, dual-source via z: out[c][r] = in[r][c] ------
// z = bz*2 + half; in += bz*inBatch + half*selIn; out += bz*outBatch + half*selOut
// If csum != null: for half==1 blocks, also accumulate column sums of the input
// (sum over rows) into csum[bz*E_ + col] via one atomicAdd per column per block.
__global__ __launch_bounds__(256) void transp2_bf16_k(const bf16_t* __restrict__ in,
                                                      long selIn, long inRow,
                                                      long inBatch,
                                                      bf16_t* __restrict__ out,
                                                      long selOut, long outRow,
                                                      long outBatch,
                                                      float* __restrict__ csum) {
  __shared__ bf16_t tile[32][33];
  __shared__ float cs[8][32];
  int r0 = blockIdx.y * 32, c0 = blockIdx.x * 32;
  int tx = threadIdx.x, ty = threadIdx.y;  // block (32,8)
  int half = blockIdx.z & 1, bz = blockIdx.z >> 1;
  long ib = (long)bz * inBatch + (long)half * selIn;
  long ob = (long)bz * outBatch + (long)half * selOut;
  float ps = 0.f;
#pragma unroll
  for (int s2 = 0; s2 < 4; ++s2) {
    bf16_t v = in[ib + (long)(r0 + ty + s2 * 8) * inRow + c0 + tx];
    tile[ty + s2 * 8][tx] = v;
    ps += (float)v;
  }
  cs[ty][tx] = ps;
  __syncthreads();
#pragma unroll
  for (int s2 = 0; s2 < 4; ++s2)
    out[ob + (long)(c0 + ty + s2 * 8) * outRow + r0 + tx] = tile[tx][ty + s2 * 8];
  if (csum && half == 1 && ty == 0) {
    float s = 0.f;
#pragma unroll
    for (int c = 0; c < 8; ++c) s += cs[c][tx];
    atomicAdd(&csum[(long)bz * E_ + c0 + tx], s);
  }
}

// ------- row softmax: read bf16 logits from fb, write fp32 f + bf16 fb -------
__global__ __launch_bounds__(256) void softmax_row_k(bf16_t* __restrict__ fb,
                                                     float* __restrict__ Fout) {
  long off = ((long)blockIdx.y * S_ + blockIdx.x) * S_;
  int t = threadIdx.x;
  bf16x8 xb = *(const bf16x8*)&fb[off + 8 * t];
  float x[8];
#pragma unroll
  for (int i = 0; i < 8; ++i) x[i] = (float)xb[i];
  float mx = fmaxf(fmaxf(fmaxf(x[0], x[1]), fmaxf(x[2], x[3])),
                   fmaxf(fmaxf(x[4], x[5]), fmaxf(x[6], x[7])));
#pragma unroll
  for (int s = 32; s >= 1; s >>= 1) mx = fmaxf(mx, __shfl_xor(mx, s));
  __shared__ float red[4];
  int wv = t >> 6;
  if ((t & 63) == 0) red[wv] = mx;
  __syncthreads();
  mx = fmaxf(fmaxf(red[0], red[1]), fmaxf(red[2], red[3]));
  float e[8];
  float sum = 0.f;
#pragma unroll
  for (int i = 0; i < 8; ++i) {
    e[i] = __expf(x[i] - mx);
    sum += e[i];
  }
#pragma unroll
  for (int s = 32; s >= 1; s >>= 1) sum += __shfl_xor(sum, s);
  __shared__ float red2[4];
  if ((t & 63) == 0) red2[wv] = sum;
  __syncthreads();
  float inv = 1.0f / ((red2[0] + red2[1]) + (red2[2] + red2[3]));
  bf16x8 ob;
#pragma unroll
  for (int i = 0; i < 8; ++i) {
    e[i] *= inv;
    ob[i] = (bf16_t)e[i];
  }
  *(float4*)&Fout[off + 8 * t] = make_float4(e[0], e[1], e[2], e[3]);
  *(float4*)&Fout[off + 8 * t + 4] = make_float4(e[4], e[5], e[6], e[7]);
  *(bf16x8*)&fb[off + 8 * t] = ob;
}

// ---- fused vq/vk small NT GEMM (64x64 tile): grid (1, S/64, 8) ----
// z = sel*4 + b; sel 0: vq = q v^T/32; sel 1: vkNeg = -k v^T/32
__global__ __launch_bounds__(256) void gemm_vqk_k(const bf16_t* __restrict__ qkb,
                                                  const bf16_t* __restrict__ vb,
                                                  bf16_t* __restrict__ vqkf) {
  __shared__ __align__(16) bf16_t As[64 * 64];
  __shared__ __align__(16) bf16_t Bs[64 * 64];
  const int zz = blockIdx.z;
  const int sel = zz >> 2;
  const int b = zz & 3;
  const bf16_t* Ab = qkb + (long)sel * BSE_ + (long)b * S_ * E_;
  const bf16_t* Bb = vb + (long)b * SVP_ * E_;
  bf16_t* outB = vqkf + ((long)b * 2 + sel) * ((long)S_ * SVP_);
  const int t = threadIdx.x;
  const int lane = t & 63;
  const int wave = t >> 6;
  const int wm = (wave & 1) * 32;
  const int wn = (wave >> 1) * 32;
  const long rowBase = (long)blockIdx.y * 64;

  floatx4 acc[2][2];
#pragma unroll
  for (int i = 0; i < 2; ++i)
#pragma unroll
    for (int j = 0; j < 2; ++j) acc[i][j] = {0.f, 0.f, 0.f, 0.f};

  const int sr = t >> 3;
  const int sc = (t & 7) * 8;
  for (int k0 = 0; k0 < E_; k0 += 64) {
#pragma unroll
    for (int p = 0; p < 2; ++p) {
      int r = p * 32 + sr;
      *(uint4*)&As[r * 64 + sc] = *(const uint4*)&Ab[(rowBase + r) * E_ + k0 + sc];
      *(uint4*)&Bs[r * 64 + sc] = *(const uint4*)&Bb[(long)r * E_ + k0 + sc];
    }
    __syncthreads();
#pragma unroll
    for (int ks = 0; ks < 64; ks += 32) {
      const int fr = lane & 15;
      const int fk = ks + ((lane >> 4) << 3);
      bf16x8 a0 = *(const bf16x8*)&As[(wm + fr) * 64 + fk];
      bf16x8 a1 = *(const bf16x8*)&As[(wm + 16 + fr) * 64 + fk];
      bf16x8 b0 = *(const bf16x8*)&Bs[(wn + fr) * 64 + fk];
      bf16x8 b1 = *(const bf16x8*)&Bs[(wn + 16 + fr) * 64 + fk];
      acc[0][0] = __builtin_amdgcn_mfma_f32_16x16x32_bf16(a0, b0, acc[0][0], 0, 0, 0);
      acc[0][1] = __builtin_amdgcn_mfma_f32_16x16x32_bf16(a0, b1, acc[0][1], 0, 0, 0);
      acc[1][0] = __builtin_amdgcn_mfma_f32_16x16x32_bf16(a1, b0, acc[1][0], 0, 0, 0);
      acc[1][1] = __builtin_amdgcn_mfma_f32_16x16x32_bf16(a1, b1, acc[1][1], 0, 0, 0);
    }
    __syncthreads();
  }

  const int cr = lane & 15;
  const int rq = (lane >> 4) * 4;
  const float alpha = sel ? -1.f / 32.f : 1.f / 32.f;
#pragma unroll
  for (int i = 0; i < 2; ++i)
#pragma unroll
    for (int j = 0; j < 2; ++j)
#pragma unroll
      for (int r = 0; r < 4; ++r) {
        long row = rowBase + wm + i * 16 + rq + r;
        int col = wn + j * 16 + cr;
        outB[row * SVP_ + col] = (bf16_t)(alpha * acc[i][j][r]);
      }
}

// ------------- fused 128x128 NT GEMM, BK=32, 2-deep prefetch pipeline -------------
// 32KB LDS/block -> 4 blocks/CU; counted vmcnt(4) keeps next tile's loads in
// flight across barriers (proven R2 structure).
// BANK-CONFLICT FIX (R5): at BK=32 a row is 64B (2 bank-groups), so constant
// chunk=hi per quarter-wave was 8-way conflicted (8.65M conflict cycles, R2).
// Read chunk c = ((row>>1)&3) ^ hi spreads each 16-lane quarter-wave 2-per-
// bank-group (free). Stage compensates on the GLOBAL source (LDS dest must stay
// linear for global_load_lds): sch = (lane&3) ^ ((lane>>3)&3). Involution
// verified: LDS(row,chunk) holds global(row, chunk^((row>>1)&3)); read of
// chunk ((row>>1)&3)^hi returns global(row,hi). The (row>>1)&3 term is
// invariant under +64 (p) and +16*wave row offsets, so one formula serves
// both staging halves and the A2/B2 tail.
__global__ __launch_bounds__(256, 4) void gemm_fused_k(
    const bf16_t* __restrict__ A1, long sA1,
    const bf16_t* __restrict__ B1, long sB1,
    int N, int K1,
    const bf16_t* __restrict__ A2q, const bf16_t* __restrict__ A2k, long sA2,
    const bf16_t* __restrict__ B2,
    float alpha, int negSplit, const float* __restrict__ colVec, long sV,
    float* __restrict__ outFa, bf16_t* __restrict__ outBa, int lda, long sOa,
    float* __restrict__ outFb, bf16_t* __restrict__ outBb, int ldb, long sOb,
    int capZ, int capM) {
  __shared__ __align__(16) bf16_t As[2 * 128 * 32];
  __shared__ __align__(16) bf16_t Bs[2 * 128 * 32];
  const int t = threadIdx.x;
  const int lane = t & 63;
  const int wave = t >> 6;
  const int wm = (wave & 1) * 64;
  const int wn = (wave >> 1) * 64;
  const long b = blockIdx.z;
  const long rowBase = (long)blockIdx.y * 128;
  const long colBase = (long)blockIdx.x * 128;
  if ((int)b >= capZ && rowBase >= capM) return;
  const bf16_t* Ab = A1 + b * sA1;
  const bf16_t* Bb = B1 + b * sB1;

  floatx4 acc[4][4];
#pragma unroll
  for (int i = 0; i < 4; ++i)
#pragma unroll
    for (int j = 0; j < 4; ++j) acc[i][j] = {0.f, 0.f, 0.f, 0.f};

  // staging: round p in {0,1}: row = p*64 + wave*16 + (lane>>2)
  // global chunk pre-swizzled so that linear LDS write + swizzled read = identity
  const int srow = lane >> 2;                          // 0..15
  const int sch = (lane & 3) ^ ((lane >> 3) & 3);      // inverse-swizzled chunk
  const bf16_t* aG = Ab + (rowBase + wave * 16 + srow) * (long)K1 + sch * 8;
  const bf16_t* bG = Bb + (colBase + wave * 16 + srow) * (long)K1 + sch * 8;
  const long rStepA = (long)64 * K1;  // p=1 row offset in global
  const int ldsW = (wave * 16) * 32;  // wave-uniform LDS base (elements)

  // frag reads: row = wm/wn + i*16 + fr, chunk = ((fr>>1)&3) ^ hi
  const int fr = lane & 15;
  const int hi = lane >> 4;
  const int ch = ((fr >> 1) & 3) ^ hi;  // swizzled chunk (row-dependent)
  int aoff[4], boff[4];
#pragma unroll
  for (int i = 0; i < 4; ++i) {
    aoff[i] = (wm + i * 16 + fr) * 32 + ch * 8;
    boff[i] = (wn + i * 16 + fr) * 32 + ch * 8;
  }

  const int nK1 = K1 >> 5;  // K-steps of 32
  const int nt = nK1 + (A2q ? 2 : 0);

  auto stage = [&](int buf, int kt) {
    const int bo = buf * (128 * 32);
    if (kt < nK1) {
      const long k0 = (long)kt * 32;
#pragma unroll
      for (int p = 0; p < 2; ++p) {
        async_copy16(aG + p * rStepA + k0, &As[bo + p * 64 * 32 + ldsW]);
        async_copy16(bG + p * rStepA + k0, &Bs[bo + p * 64 * 32 + ldsW]);
      }
    } else {  // two 32-wide K tail steps from A2/B2 (row stride 64)
      const int ts = kt - nK1;  // 0 or 1
      const bf16_t* A2 = (colBase >= negSplit) ? A2k : A2q;
      const bf16_t* A2b = A2 + b * sA2;
#pragma unroll
      for (int p = 0; p < 2; ++p) {
        long r = rowBase + p * 64 + wave * 16 + srow;
        long rc = colBase + p * 64 + wave * 16 + srow;
        async_copy16(A2b + r * 64 + ts * 32 + sch * 8, &As[bo + p * 64 * 32 + ldsW]);
        async_copy16(B2 + rc * 64 + ts * 32 + sch * 8, &Bs[bo + p * 64 * 32 + ldsW]);
      }
    }
  };

  // prologue: tiles 0 and 1 in flight (4 loads each)
  stage(0, 0);
  if (nt > 1) stage(1, 1);

  for (int kt = 0; kt < nt; ++kt) {
    // retire only the current tile's 4 loads; keep next tile's in flight (T4)
    if (kt < nt - 1)
      asm volatile("s_waitcnt vmcnt(4)" ::: "memory");
    else
      asm volatile("s_waitcnt vmcnt(0)" ::: "memory");
    __builtin_amdgcn_s_barrier();
    __builtin_amdgcn_sched_barrier(0);
    const int bo = (kt & 1) * (128 * 32);
    __builtin_amdgcn_s_setprio(1);
    {
      bf16x8 af[4], bfr[4];
#pragma unroll
      for (int i = 0; i < 4; ++i) af[i] = *(const bf16x8*)&As[bo + aoff[i]];
#pragma unroll
      for (int i = 0; i < 4; ++i) bfr[i] = *(const bf16x8*)&Bs[bo + boff[i]];
#pragma unroll
      for (int i = 0; i < 4; ++i)
#pragma unroll
        for (int j = 0; j < 4; ++j)
          acc[i][j] =
              __builtin_amdgcn_mfma_f32_16x16x32_bf16(af[i], bfr[j], acc[i][j], 0, 0, 0);
    }
    __builtin_amdgcn_s_setprio(0);
    __builtin_amdgcn_sched_barrier(0);
    __builtin_amdgcn_s_barrier();  // all waves done reading buf[kt&1]
    __builtin_amdgcn_sched_barrier(0);
    if (kt + 2 < nt) stage(kt & 1, kt + 2);
  }

  // ---- epilogue ----
  const int cr = lane & 15;
  const int rq = hi * 4;
  const bool neg = (colBase >= negSplit);
  const float* cv = colVec ? (colVec + b * sV + (neg ? colBase - negSplit : colBase))
                           : nullptr;
  float* oF = neg ? outFb : outFa;
  bf16_t* oB = neg ? outBb : outBa;
  const int ld = neg ? ldb : lda;
  const long sO = neg ? sOb : sOa;
  const long cb0 = neg ? (long)(colBase - negSplit) : colBase;
#pragma unroll
  for (int i = 0; i < 4; ++i)
#pragma unroll
    for (int j = 0; j < 4; ++j)
#pragma unroll
      for (int r = 0; r < 4; ++r) {
        long row = rowBase + wm + i * 16 + rq + r;
        int c = wn + j * 16 + cr;
        float v = alpha * acc[i][j][r];
        if (neg) v = cv[c] - v;
        long o = b * sO + row * (long)ld + cb0 + c;
        if (oF) oF[o] = v;
        if (oB) oB[o] = (bf16_t)v;
      }
}

extern "C" void kernel_launch(void* const* d_in, const int* in_sizes, int n_in,
                              void* d_out, int out_size, void* d_ws, size_t ws_size,
                              hipStream_t stream) {
  const float* Q = (const float*)d_in[0];
  const float* Kin = (const float*)d_in[1];
  const float* V = (const float*)d_in[2];
  const float* W_Q = (const float*)d_in[3];
  const float* W_K = (const float*)d_in[4];
  const float* W_v = (const float*)d_in[5];
  const float* W_vq = (const float*)d_in[6];
  const float* W_vk = (const float*)d_in[7];

  float* Qout = (float*)d_out;              // [4,2048,1024]
  float* Kout = Qout + (long)B_ * S_ * E_;  // [4,2048,1024]
  float* Fout = Kout + (long)B_ * S_ * E_;  // [4,2048,2048] fp32 f

  char* w = (char*)d_ws;
  auto alloc = [&](size_t bytes) {
    char* p = w;
    w += (bytes + 255) & ~(size_t)255;
    return p;
  };
  const long BSE = BSE_;
  // NOTE: WQKt/WVt contiguous, QtKt/Vt contiguous, qkb/vb contiguous — the
  // merged projection dispatch (z=3) relies on these adjacencies. ck/ck2
  // contiguous — single memset covers both.
  bf16_t* WQKt = (bf16_t*)alloc((size_t)2 * 2 * E_ * E_);   // [WQt | WKt], each [E,E]
  bf16_t* WVt = (bf16_t*)alloc((size_t)2 * E_ * E_);        // [E,E] == WQKt + 2*E*E
  bf16_t* Wv2T = (bf16_t*)alloc((size_t)2 * 2 * E_ * SVP_); // [2E,64]: Wvq^T ; Wvk^T
  bf16_t* QtKt = (bf16_t*)alloc((size_t)2 * 2 * BSE);       // tanh(Q);tanh(K) [16384,E]
  bf16_t* Vt = (bf16_t*)alloc((size_t)2 * B_ * SVP_ * E_);  // [256,E] == QtKt + 2*BSE
  bf16_t* qkb = (bf16_t*)alloc((size_t)2 * 2 * BSE);        // q ; k   [16384,E]
  bf16_t* vb = (bf16_t*)alloc((size_t)2 * B_ * SVP_ * E_);  // v [256,E] == qkb + 2*BSE
  bf16_t* qkT = (bf16_t*)alloc((size_t)2 * (long)B_ * 2 * E_ * S_);  // [b][2E][S]
  bf16_t* fb = (bf16_t*)alloc((size_t)2 * (long)B_ * S_ * S_);       // logits -> f bf16
  bf16_t* vqkf = (bf16_t*)alloc((size_t)2 * (long)B_ * 2 * S_ * SVP_); // [b][2S][64]
  bf16_t* q2k2 = (bf16_t*)alloc((size_t)2 * (long)B_ * S_ * 2 * E_);   // [b][S][2E]
  bf16_t* q2k2T = (bf16_t*)alloc((size_t)2 * (long)B_ * 2 * E_ * S_);  // [b][2E][S]
  float* ck = (float*)alloc((size_t)4 * B_ * E_);
  float* ck2 = (float*)alloc((size_t)4 * B_ * E_);

  bf16_t* qb = qkb;
  bf16_t* kb = qkb + BSE;

  dim3 blk256(256);
  dim3 blk32x8(32, 8);

  // ---- zero colsum accumulators (ck | ck2 contiguous) ----
  hipMemsetAsync(ck, 0, (size_t)2 * 4 * B_ * E_, stream);

  // ---- weight prep (merged: 2 dispatches) ----
  transp_cast3_k<<<dim3(32, 32, 3), blk32x8, 0, stream>>>(W_Q, W_K, W_v, WQKt,
                                                          E_, E_, E_);
  transp_cast3_k<<<dim3(32, 2, 2), blk32x8, 0, stream>>>(W_vq, W_vk, W_vq, Wv2T,
                                                         SV_, E_, SVP_);

  // ---- tanh + cast inputs ----
  tanh2_k<<<dim3((unsigned)(2 * BSE / 1024)), blk256, 0, stream>>>(Q, Kin, QtKt);
  tanh_vpad_k<<<dim3(B_ * SVP_ * E_ / 256), blk256, 0, stream>>>(V, Vt);

  // ---- Q,K,V projections fused via z (0: Qt@WQt, 1: Kt@WKt, 2: Vt@WVt) ----
  gemm_fused_k<<<dim3(E_ / 128, B_ * S_ / 128, 3), blk256, 0, stream>>>(
      QtKt, BSE, WQKt, (long)E_ * E_, E_, E_,
      nullptr, nullptr, 0, nullptr, 1.f, E_, nullptr, 0,
      nullptr, qkb, E_, BSE, nullptr, nullptr, 0, 0,
      /*capZ=*/2, /*capM=*/B_ * SVP_);

  // ---- qkT = [q^T ; k^T] per batch [2E,S]; fused colsum(k) -> ck ----
  transp2_bf16_k<<<dim3(E_ / 32, S_ / 32, 2 * B_), blk32x8, 0, stream>>>(
      qkb, BSE, E_, (long)S_ * E_, qkT, (long)E_ * S_, S_, (long)2 * E_ * S_, ck);

  // ---- logits = q k^T / 32 -> fb (bf16); softmax reads fb, writes Fout + fb ----
  gemm_fused_k<<<dim3(S_ / 128, S_ / 128, B_), blk256, 0, stream>>>(
      qb, (long)S_ * E_, kb, (long)S_ * E_, S_, E_,
      nullptr, nullptr, 0, nullptr, 1.f / 32.f, S_, nullptr, 0,
      nullptr, fb, S_, (long)S_ * S_, nullptr, nullptr, 0, 0,
      9999, 0);
  softmax_row_k<<<dim3(S_, B_), blk256, 0, stream>>>(fb, Fout);

  // ---- vq = q v^T/32 ; vkNeg = -k v^T/32 -> vqkf [b][2S][64] (one dispatch) ----
  gemm_vqk_k<<<dim3(1, S_ / 64, 2 * B_), blk256, 0, stream>>>(qkb, vb, vqkf);

  // ---- q2|k2 = [f@q + vq@Wvq | ck - (f@k - vk@Wvk)]  (one dispatch) ----
  gemm_fused_k<<<dim3(2 * E_ / 128, S_ / 128, B_), blk256, 0, stream>>>(
      fb, (long)S_ * S_, qkT, (long)2 * E_ * S_, 2 * E_, S_,
      vqkf, vqkf + (long)S_ * SVP_, (long)2 * S_ * SVP_, Wv2T,
      1.f, E_, ck, E_,
      nullptr, q2k2, 2 * E_, (long)S_ * 2 * E_,
      nullptr, q2k2 + E_, 2 * E_, (long)S_ * 2 * E_,
      9999, 0);

  // ---- q2k2T = [q2^T ; k2^T]; fused colsum(k2) -> ck2 ----
  transp2_bf16_k<<<dim3(E_ / 32, S_ / 32, 2 * B_), blk32x8, 0, stream>>>(
      q2k2, E_, 2 * E_, (long)S_ * 2 * E_, q2k2T, (long)E_ * S_, S_,
      (long)2 * E_ * S_, ck2);

  // ---- Q_out = f@q2 ; K_out = ck2 - f@k2  (one dispatch) ----
  gemm_fused_k<<<dim3(2 * E_ / 128, S_ / 128, B_), blk256, 0, stream>>>(
      fb, (long)S_ * S_, q2k2T, (long)2 * E_ * S_, 2 * E_, S_,
      nullptr, nullptr, 0, nullptr,
      1.f, E_, ck2, E_,
      Qout, nullptr, E_, (long)S_ * E_,
      Kout, nullptr, E_, (long)S_ * E_,
      9999, 0);
}

// Round 10
// 572.864 us; speedup vs baseline: 1.0126x; 1.0126x over previous
//
#include <hip/hip_runtime.h>
#include <cstdint>
#include <cstddef>

typedef __bf16 bf16_t;
typedef __bf16 bf16x4 __attribute__((ext_vector_type(4)));
typedef __bf16 bf16x8 __attribute__((ext_vector_type(8)));
typedef float floatx4 __attribute__((ext_vector_type(4)));

#define B_ 4
#define S_ 2048
#define E_ 1024
#define SV_ 50
#define SVP_ 64
#define BSE_ ((long)B_ * S_ * E_)

__device__ __forceinline__ void async_copy16(const bf16_t* g, bf16_t* l) {
  __builtin_amdgcn_global_load_lds(
      (const __attribute__((address_space(1))) void*)g,
      (__attribute__((address_space(3))) void*)l, 16, 0, 0);
}

// ---------------- tanh of Q and K (concat), float4 vectorized ----------------
__global__ __launch_bounds__(256) void tanh2_k(const float* __restrict__ Q,
                                               const float* __restrict__ Kin,
                                               bf16_t* __restrict__ out) {
  long i4 = ((long)blockIdx.x * 256 + threadIdx.x) * 4;
  const long n = (long)B_ * S_ * E_;
  const float* src = (i4 < n) ? (Q + i4) : (Kin + (i4 - n));
  float4 x = *(const float4*)src;
  bf16x4 o;
  o[0] = (bf16_t)tanhf(x.x);
  o[1] = (bf16_t)tanhf(x.y);
  o[2] = (bf16_t)tanhf(x.z);
  o[3] = (bf16_t)tanhf(x.w);
  *(bf16x4*)&out[i4] = o;
}

// V [B,50,1024] -> tanh, padded to [B,64,1024] with zero rows
__global__ __launch_bounds__(256) void tanh_vpad_k(const float* __restrict__ V,
                                                   bf16_t* __restrict__ out) {
  int i = blockIdx.x * 256 + threadIdx.x;  // covers B*64*1024
  int e = i & 1023, r = (i >> 10) & 63, b = i >> 16;
  float v = 0.f;
  if (r < SV_) v = tanhf(V[((long)(b * SV_ + r) << 10) + e]);
  out[i] = (bf16_t)v;
}

// ------- W [K,N] fp32 -> Wt [N,Kp] bf16 (zero-pad k>=K); 3-way z select -------
__global__ __launch_bounds__(256) void transp_cast3_k(const float* __restrict__ W0,
                                                      const float* __restrict__ W1,
                                                      const float* __restrict__ W2,
                                                      bf16_t* __restrict__ out,
                                                      int K, int N, int Kp) {
  __shared__ float tile[32][33];
  const float* W = (blockIdx.z == 0) ? W0 : (blockIdx.z == 1) ? W1 : W2;
  bf16_t* o = out + (long)blockIdx.z * N * Kp;
  int k0 = blockIdx.y * 32, n0 = blockIdx.x * 32;
  int tx = threadIdx.x, ty = threadIdx.y;  // block (32,8)
#pragma unroll
  for (int s2 = 0; s2 < 4; ++s2) {
    int kk = ty + s2 * 8;
    float v = 0.f;
    if (k0 + kk < K && n0 + tx < N) v = W[(long)(k0 + kk) * N + n0 + tx];
    tile[kk][tx] = v;
  }
  __syncthreads();
#pragma unroll
  for (int s2 = 0; s2 < 4; ++s2) {
    int nn = ty + s2 * 8;
    if (n0 + nn < N && k0 + tx < Kp)
      o[(long)(n0 + nn) * Kp + k0 + tx] = (bf16_t)tile[tx][nn];
  }
}

// ------ strided bf16 transpose, dual-source via z: out[c][r] = in[r][c] ------
// If csum != null: for half==1 blocks, also accumulate column sums of the input
// into csum[bz*E_ + col] via one atomicAdd per column per block.
__global__ __launch_bounds__(256) void transp2_bf16_k(const bf16_t* __restrict__ in,
                                                      long selIn, long inRow,
                                                      long inBatch,
                                                      bf16_t* __restrict__ out,
                                                      long selOut, long outRow,
                                                      long outBatch,
                                                      float* __restrict__ csum) {
  __shared__ bf16_t tile[32][33];
  __shared__ float cs[8][32];
  int r0 = blockIdx.y * 32, c0 = blockIdx.x * 32;
  int tx = threadIdx.x, ty = threadIdx.y;  // block (32,8)
  int half = blockIdx.z & 1, bz = blockIdx.z >> 1;
  long ib = (long)bz * inBatch + (long)half * selIn;
  long ob = (long)bz * outBatch + (long)half * selOut;
  float ps = 0.f;
#pragma unroll
  for (int s2 = 0; s2 < 4; ++s2) {
    bf16_t v = in[ib + (long)(r0 + ty + s2 * 8) * inRow + c0 + tx];
    tile[ty + s2 * 8][tx] = v;
    ps += (float)v;
  }
  cs[ty][tx] = ps;
  __syncthreads();
#pragma unroll
  for (int s2 = 0; s2 < 4; ++s2)
    out[ob + (long)(c0 + ty + s2 * 8) * outRow + r0 + tx] = tile[tx][ty + s2 * 8];
  if (csum && half == 1 && ty == 0) {
    float s = 0.f;
#pragma unroll
    for (int c = 0; c < 8; ++c) s += cs[c][tx];
    atomicAdd(&csum[(long)bz * E_ + c0 + tx], s);
  }
}

// ------- row softmax: read bf16 logits from fb, write fp32 f + bf16 fb -------
__global__ __launch_bounds__(256) void softmax_row_k(bf16_t* __restrict__ fb,
                                                     float* __restrict__ Fout) {
  long off = ((long)blockIdx.y * S_ + blockIdx.x) * S_;
  int t = threadIdx.x;
  bf16x8 xb = *(const bf16x8*)&fb[off + 8 * t];
  float x[8];
#pragma unroll
  for (int i = 0; i < 8; ++i) x[i] = (float)xb[i];
  float mx = fmaxf(fmaxf(fmaxf(x[0], x[1]), fmaxf(x[2], x[3])),
                   fmaxf(fmaxf(x[4], x[5]), fmaxf(x[6], x[7])));
#pragma unroll
  for (int s = 32; s >= 1; s >>= 1) mx = fmaxf(mx, __shfl_xor(mx, s));
  __shared__ float red[4];
  int wv = t >> 6;
  if ((t & 63) == 0) red[wv] = mx;
  __syncthreads();
  mx = fmaxf(fmaxf(red[0], red[1]), fmaxf(red[2], red[3]));
  float e[8];
  float sum = 0.f;
#pragma unroll
  for (int i = 0; i < 8; ++i) {
    e[i] = __expf(x[i] - mx);
    sum += e[i];
  }
#pragma unroll
  for (int s = 32; s >= 1; s >>= 1) sum += __shfl_xor(sum, s);
  __shared__ float red2[4];
  if ((t & 63) == 0) red2[wv] = sum;
  __syncthreads();
  float inv = 1.0f / ((red2[0] + red2[1]) + (red2[2] + red2[3]));
  bf16x8 ob;
#pragma unroll
  for (int i = 0; i < 8; ++i) {
    e[i] *= inv;
    ob[i] = (bf16_t)e[i];
  }
  *(float4*)&Fout[off + 8 * t] = make_float4(e[0], e[1], e[2], e[3]);
  *(float4*)&Fout[off + 8 * t + 4] = make_float4(e[4], e[5], e[6], e[7]);
  *(bf16x8*)&fb[off + 8 * t] = ob;
}

// ---- fused vq/vk small NT GEMM (64x64 tile): grid (1, S/64, 8) ----
// z = sel*4 + b; sel 0: vq = q v^T/32; sel 1: vkNeg = -k v^T/32
__global__ __launch_bounds__(256) void gemm_vqk_k(const bf16_t* __restrict__ qkb,
                                                  const bf16_t* __restrict__ vb,
                                                  bf16_t* __restrict__ vqkf) {
  __shared__ __align__(16) bf16_t As[64 * 64];
  __shared__ __align__(16) bf16_t Bs[64 * 64];
  const int zz = blockIdx.z;
  const int sel = zz >> 2;
  const int b = zz & 3;
  const bf16_t* Ab = qkb + (long)sel * BSE_ + (long)b * S_ * E_;
  const bf16_t* Bb = vb + (long)b * SVP_ * E_;
  bf16_t* outB = vqkf + ((long)b * 2 + sel) * ((long)S_ * SVP_);
  const int t = threadIdx.x;
  const int lane = t & 63;
  const int wave = t >> 6;
  const int wm = (wave & 1) * 32;
  const int wn = (wave >> 1) * 32;
  const long rowBase = (long)blockIdx.y * 64;

  floatx4 acc[2][2];
#pragma unroll
  for (int i = 0; i < 2; ++i)
#pragma unroll
    for (int j = 0; j < 2; ++j) acc[i][j] = {0.f, 0.f, 0.f, 0.f};

  const int sr = t >> 3;
  const int sc = (t & 7) * 8;
  for (int k0 = 0; k0 < E_; k0 += 64) {
#pragma unroll
    for (int p = 0; p < 2; ++p) {
      int r = p * 32 + sr;
      *(uint4*)&As[r * 64 + sc] = *(const uint4*)&Ab[(rowBase + r) * E_ + k0 + sc];
      *(uint4*)&Bs[r * 64 + sc] = *(const uint4*)&Bb[(long)r * E_ + k0 + sc];
    }
    __syncthreads();
#pragma unroll
    for (int ks = 0; ks < 64; ks += 32) {
      const int fr = lane & 15;
      const int fk = ks + ((lane >> 4) << 3);
      bf16x8 a0 = *(const bf16x8*)&As[(wm + fr) * 64 + fk];
      bf16x8 a1 = *(const bf16x8*)&As[(wm + 16 + fr) * 64 + fk];
      bf16x8 b0 = *(const bf16x8*)&Bs[(wn + fr) * 64 + fk];
      bf16x8 b1 = *(const bf16x8*)&Bs[(wn + 16 + fr) * 64 + fk];
      acc[0][0] = __builtin_amdgcn_mfma_f32_16x16x32_bf16(a0, b0, acc[0][0], 0, 0, 0);
      acc[0][1] = __builtin_amdgcn_mfma_f32_16x16x32_bf16(a0, b1, acc[0][1], 0, 0, 0);
      acc[1][0] = __builtin_amdgcn_mfma_f32_16x16x32_bf16(a1, b0, acc[1][0], 0, 0, 0);
      acc[1][1] = __builtin_amdgcn_mfma_f32_16x16x32_bf16(a1, b1, acc[1][1], 0, 0, 0);
    }
    __syncthreads();
  }

  const int cr = lane & 15;
  const int rq = (lane >> 4) * 4;
  const float alpha = sel ? -1.f / 32.f : 1.f / 32.f;
#pragma unroll
  for (int i = 0; i < 2; ++i)
#pragma unroll
    for (int j = 0; j < 2; ++j)
#pragma unroll
      for (int r = 0; r < 4; ++r) {
        long row = rowBase + wm + i * 16 + rq + r;
        int col = wn + j * 16 + cr;
        outB[row * SVP_ + col] = (bf16_t)(alpha * acc[i][j][r]);
      }
}

// ============ 256x256 NT GEMM, 512 thr / 8 waves, BK=64, 4-phase pipeline ============
// Derived from the 8-phase 256-sq template. 128 KB LDS (2 x dbuf x [256][64] A,B),
// 1 block/CU. Per-wave output 128x64 (wr=wave>>2 in {0,1}, wc=wave&3 in 0..3).
// Schedule per K-tile (4 phases, C-quadrants):
//   P1: burst-stage ALL 8 half-rows of tile t+1 into buf^1 (non-final tiles);
//       s_waitcnt vmcnt(8) retires tile t's 8 loads, t+1's stay in flight
//       (final tile: no stage, vmcnt(0) full drain -> no in-flight LDS-DMA at
//       s_endpgm, which could corrupt the next workgroup's LDS); barrier;
//       ds a(i0-3)+b(j0-1); MFMA 16.
//   P2: barrier; ds b(j2-3); MFMA 16 (a held).
//   P3: barrier; ds a(i4-7); MFMA 16 (b1 held).
//   P4: barrier; MFMA 16 (a1,b0 held; no LDS reads).
// Safety: stage(t+1->buf^1) issues after t-1's last reads (fenced by t's
// P4-start barrier in the previous frame); vmcnt(8)+barrier precedes any read
// of tile t; buf overwrite (t+2 stage) fenced from t's last read (P3) by t's
// P4-start barrier. Invariant: 8 loads outstanding at every non-final boundary.
// Swizzle: LDS(r,c) holds global(r, c ^ (r&7)) via pre-swizzled GLOBAL source
// (sch = (t&7) ^ (srow&7)); read chunk = hi ^ (fr&7) returns global chunk hi.
// Quarter-wave reads: 2 lanes per 16B slot -> conflict-free (R5-proven class).
__global__ __launch_bounds__(512, 2) void gemm256_k(
    const bf16_t* __restrict__ A1, long sA1,
    const bf16_t* __restrict__ B1, long sB1,
    int N, int K1,
    const bf16_t* __restrict__ A2q, const bf16_t* __restrict__ A2k, long sA2,
    const bf16_t* __restrict__ B2,
    float alpha, int negSplit, const float* __restrict__ colVec, long sV,
    float* __restrict__ outFa, bf16_t* __restrict__ outBa, int lda, long sOa,
    float* __restrict__ outFb, bf16_t* __restrict__ outBb, int ldb, long sOb,
    int capZ, int capM) {
  __shared__ __align__(16) bf16_t As[2 * 256 * 64];
  __shared__ __align__(16) bf16_t Bs[2 * 256 * 64];
  const int t = threadIdx.x;
  const int lane = t & 63;
  const int wave = t >> 6;  // 0..7
  const int wr = wave >> 2; // 0..1
  const int wc = wave & 3;  // 0..3
  const long b = blockIdx.z;
  const long rowBase = (long)blockIdx.y * 256;
  const long colBase = (long)blockIdx.x * 256;
  if ((int)b >= capZ && rowBase >= capM) return;
  const bf16_t* Ab = A1 + b * sA1;
  const bf16_t* Bb = B1 + b * sB1;

  floatx4 acc[8][4];
#pragma unroll
  for (int i = 0; i < 8; ++i)
#pragma unroll
    for (int j = 0; j < 4; ++j) acc[i][j] = {0.f, 0.f, 0.f, 0.f};

  // ---- staging geometry: thread covers row srow (+64*h), chunk pre-swizzled ----
  const int srow = t >> 3;                        // 0..63
  const int sch = (t & 7) ^ (srow & 7);           // inverse-swizzled 16B chunk
  const bf16_t* aG = Ab + (rowBase + srow) * (long)K1 + sch * 8;
  const bf16_t* bG = Bb + (colBase + srow) * (long)K1 + sch * 8;
  const bf16_t* A2 = A2q ? ((colBase >= negSplit) ? A2k : A2q) : nullptr;
  const bf16_t* a2G = A2 ? A2 + b * sA2 + (rowBase + srow) * 64 + sch * 8 : aG;
  const bf16_t* b2G = A2 ? B2 + (colBase + srow) * 64 + sch * 8 : bG;
  const int ldsW = (wave * 8) * 64;  // wave-uniform LDS base (elements)

  // ---- frag read offsets: row stride 64 elem, swizzled chunk ----
  const int fr = lane & 15;
  const int hi = lane >> 4;  // 0..3
  const int swz = (hi ^ (fr & 7)) * 8;
  int aoff[8], boff[4];
#pragma unroll
  for (int i = 0; i < 8; ++i) aoff[i] = (wr * 128 + i * 16 + fr) * 64 + swz;
#pragma unroll
  for (int j = 0; j < 4; ++j) boff[j] = (wc * 64 + j * 16 + fr) * 64 + swz;

  const int nK1 = K1 >> 6;
  const int nt = nK1 + (A2q ? 1 : 0);

  auto stageTile = [&](int buf, int kt) {
    const int bo = buf * (256 * 64);
    bf16_t* la = &As[bo + ldsW];
    bf16_t* lb = &Bs[bo + ldsW];
    if (kt < nK1) {
      const long k0 = (long)kt * 64;
#pragma unroll
      for (int h = 0; h < 4; ++h) {
        async_copy16(aG + (long)(h * 64) * K1 + k0, la + h * 64 * 64);
        async_copy16(bG + (long)(h * 64) * K1 + k0, lb + h * 64 * 64);
      }
    } else {  // 64-wide K tail from A2/B2 (row stride 64)
#pragma unroll
      for (int h = 0; h < 4; ++h) {
        async_copy16(a2G + h * 64 * 64, la + h * 64 * 64);
        async_copy16(b2G + h * 64 * 64, lb + h * 64 * 64);
      }
    }
  };

  // prologue: tile 0 fully staged (8 loads in flight)
  stageTile(0, 0);

  for (int kt = 0; kt < nt; ++kt) {
    const int bo = (kt & 1) * (256 * 64);
    bf16x8 a0l[4], a0h[4], a1l[4], a1h[4], b0l[2], b0h[2], b1l[2], b1h[2];

    // ---- P1: stage burst (t+1) if any, retire tile t's loads, quadrant (i0-3,j0-1)
    if (kt + 1 < nt) {
      stageTile((kt + 1) & 1, kt + 1);
      asm volatile("s_waitcnt vmcnt(8)" ::: "memory");
    } else {
      asm volatile("s_waitcnt vmcnt(0)" ::: "memory");  // full drain before exit
    }
    __builtin_amdgcn_s_barrier();
    __builtin_amdgcn_sched_barrier(0);
#pragma unroll
    for (int i = 0; i < 4; ++i) {
      a0l[i] = *(const bf16x8*)&As[bo + aoff[i]];
      a0h[i] = *(const bf16x8*)&As[bo + (aoff[i] ^ 32)];
    }
#pragma unroll
    for (int j = 0; j < 2; ++j) {
      b0l[j] = *(const bf16x8*)&Bs[bo + boff[j]];
      b0h[j] = *(const bf16x8*)&Bs[bo + (boff[j] ^ 32)];
    }
    __builtin_amdgcn_s_setprio(1);
#pragma unroll
    for (int i = 0; i < 4; ++i)
#pragma unroll
      for (int j = 0; j < 2; ++j) {
        acc[i][j] = __builtin_amdgcn_mfma_f32_16x16x32_bf16(a0l[i], b0l[j], acc[i][j], 0, 0, 0);
        acc[i][j] = __builtin_amdgcn_mfma_f32_16x16x32_bf16(a0h[i], b0h[j], acc[i][j], 0, 0, 0);
      }
    __builtin_amdgcn_s_setprio(0);
    __builtin_amdgcn_sched_barrier(0);

    // ---- P2: quadrant (i0-3, j2-3), a0 held
    __builtin_amdgcn_s_barrier();
    __builtin_amdgcn_sched_barrier(0);
#pragma unroll
    for (int j = 0; j < 2; ++j) {
      b1l[j] = *(const bf16x8*)&Bs[bo + boff[j + 2]];
      b1h[j] = *(const bf16x8*)&Bs[bo + (boff[j + 2] ^ 32)];
    }
    __builtin_amdgcn_s_setprio(1);
#pragma unroll
    for (int i = 0; i < 4; ++i)
#pragma unroll
      for (int j = 0; j < 2; ++j) {
        acc[i][j + 2] = __builtin_amdgcn_mfma_f32_16x16x32_bf16(a0l[i], b1l[j], acc[i][j + 2], 0, 0, 0);
        acc[i][j + 2] = __builtin_amdgcn_mfma_f32_16x16x32_bf16(a0h[i], b1h[j], acc[i][j + 2], 0, 0, 0);
      }
    __builtin_amdgcn_s_setprio(0);
    __builtin_amdgcn_sched_barrier(0);

    // ---- P3: quadrant (i4-7, j2-3), b1 held; LAST LDS reads of tile t
    __builtin_amdgcn_s_barrier();
    __builtin_amdgcn_sched_barrier(0);
#pragma unroll
    for (int i = 0; i < 4; ++i) {
      a1l[i] = *(const bf16x8*)&As[bo + aoff[i + 4]];
      a1h[i] = *(const bf16x8*)&As[bo + (aoff[i + 4] ^ 32)];
    }
    __builtin_amdgcn_s_setprio(1);
#pragma unroll
    for (int i = 0; i < 4; ++i)
#pragma unroll
      for (int j = 0; j < 2; ++j) {
        acc[i + 4][j + 2] = __builtin_amdgcn_mfma_f32_16x16x32_bf16(a1l[i], b1l[j], acc[i + 4][j + 2], 0, 0, 0);
        acc[i + 4][j + 2] = __builtin_amdgcn_mfma_f32_16x16x32_bf16(a1h[i], b1h[j], acc[i + 4][j + 2], 0, 0, 0);
      }
    __builtin_amdgcn_s_setprio(0);
    __builtin_amdgcn_sched_barrier(0);

    // ---- P4: quadrant (i4-7, j0-1), a1+b0 held; start-barrier fences t's reads
    __builtin_amdgcn_s_barrier();
    __builtin_amdgcn_sched_barrier(0);
    __builtin_amdgcn_s_setprio(1);
#pragma unroll
    for (int i = 0; i < 4; ++i)
#pragma unroll
      for (int j = 0; j < 2; ++j) {
        acc[i + 4][j] = __builtin_amdgcn_mfma_f32_16x16x32_bf16(a1l[i], b0l[j], acc[i + 4][j], 0, 0, 0);
        acc[i + 4][j] = __builtin_amdgcn_mfma_f32_16x16x32_bf16(a1h[i], b0h[j], acc[i + 4][j], 0, 0, 0);
      }
    __builtin_amdgcn_s_setprio(0);
    __builtin_amdgcn_sched_barrier(0);
  }

  // ---- epilogue ----
  const int cr = lane & 15;
  const int rq = hi * 4;
  const bool neg = (colBase >= negSplit);
  const float* cv = colVec ? (colVec + b * sV + (neg ? colBase - negSplit : colBase))
                           : nullptr;
  float* oF = neg ? outFb : outFa;
  bf16_t* oB = neg ? outBb : outBa;
  const int ld = neg ? ldb : lda;
  const long sO = neg ? sOb : sOa;
  const long cb0 = neg ? (long)(colBase - negSplit) : colBase;
#pragma unroll
  for (int i = 0; i < 8; ++i)
#pragma unroll
    for (int j = 0; j < 4; ++j)
#pragma unroll
      for (int r = 0; r < 4; ++r) {
        long row = rowBase + wr * 128 + i * 16 + rq + r;
        int c = wc * 64 + j * 16 + cr;
        float v = alpha * acc[i][j][r];
        if (neg) v = cv[c] - v;
        long o = b * sO + row * (long)ld + cb0 + c;
        if (oF) oF[o] = v;
        if (oB) oB[o] = (bf16_t)v;
      }
}

extern "C" void kernel_launch(void* const* d_in, const int* in_sizes, int n_in,
                              void* d_out, int out_size, void* d_ws, size_t ws_size,
                              hipStream_t stream) {
  const float* Q = (const float*)d_in[0];
  const float* Kin = (const float*)d_in[1];
  const float* V = (const float*)d_in[2];
  const float* W_Q = (const float*)d_in[3];
  const float* W_K = (const float*)d_in[4];
  const float* W_v = (const float*)d_in[5];
  const float* W_vq = (const float*)d_in[6];
  const float* W_vk = (const float*)d_in[7];

  float* Qout = (float*)d_out;              // [4,2048,1024]
  float* Kout = Qout + (long)B_ * S_ * E_;  // [4,2048,1024]
  float* Fout = Kout + (long)B_ * S_ * E_;  // [4,2048,2048] fp32 f

  char* w = (char*)d_ws;
  auto alloc = [&](size_t bytes) {
    char* p = w;
    w += (bytes + 255) & ~(size_t)255;
    return p;
  };
  const long BSE = BSE_;
  bf16_t* WQKt = (bf16_t*)alloc((size_t)2 * 2 * E_ * E_);   // [WQt | WKt], each [E,E]
  bf16_t* WVt = (bf16_t*)alloc((size_t)2 * E_ * E_);        // [E,E] == WQKt + 2*E*E
  bf16_t* Wv2T = (bf16_t*)alloc((size_t)2 * 2 * E_ * SVP_); // [2E,64]: Wvq^T ; Wvk^T
  bf16_t* QtKt = (bf16_t*)alloc((size_t)2 * 2 * BSE);       // tanh(Q);tanh(K) [16384,E]
  bf16_t* Vt = (bf16_t*)alloc((size_t)2 * B_ * SVP_ * E_);  // [256,E] == QtKt + 2*BSE
  bf16_t* qkb = (bf16_t*)alloc((size_t)2 * 2 * BSE);        // q ; k   [16384,E]
  bf16_t* vb = (bf16_t*)alloc((size_t)2 * B_ * SVP_ * E_);  // v [256,E] == qkb + 2*BSE
  bf16_t* qkT = (bf16_t*)alloc((size_t)2 * (long)B_ * 2 * E_ * S_);  // [b][2E][S]
  bf16_t* fb = (bf16_t*)alloc((size_t)2 * (long)B_ * S_ * S_);       // logits -> f bf16
  bf16_t* vqkf = (bf16_t*)alloc((size_t)2 * (long)B_ * 2 * S_ * SVP_); // [b][2S][64]
  bf16_t* q2k2 = (bf16_t*)alloc((size_t)2 * (long)B_ * S_ * 2 * E_);   // [b][S][2E]
  bf16_t* q2k2T = (bf16_t*)alloc((size_t)2 * (long)B_ * 2 * E_ * S_);  // [b][2E][S]
  float* ck = (float*)alloc((size_t)4 * B_ * E_);
  float* ck2 = (float*)alloc((size_t)4 * B_ * E_);

  bf16_t* qb = qkb;
  bf16_t* kb = qkb + BSE;

  dim3 blk256(256);
  dim3 blk512(512);
  dim3 blk32x8(32, 8);

  // ---- zero colsum accumulators (ck | ck2 contiguous) ----
  hipMemsetAsync(ck, 0, (size_t)2 * 4 * B_ * E_, stream);

  // ---- weight prep (merged: 2 dispatches) ----
  transp_cast3_k<<<dim3(32, 32, 3), blk32x8, 0, stream>>>(W_Q, W_K, W_v, WQKt,
                                                          E_, E_, E_);
  transp_cast3_k<<<dim3(32, 2, 2), blk32x8, 0, stream>>>(W_vq, W_vk, W_vq, Wv2T,
                                                         SV_, E_, SVP_);

  // ---- tanh + cast inputs ----
  tanh2_k<<<dim3((unsigned)(2 * BSE / 1024)), blk256, 0, stream>>>(Q, Kin, QtKt);
  tanh_vpad_k<<<dim3(B_ * SVP_ * E_ / 256), blk256, 0, stream>>>(V, Vt);

  // ---- Q,K,V projections fused via z (0: Qt@WQt, 1: Kt@WKt, 2: Vt@WVt) ----
  gemm256_k<<<dim3(E_ / 256, B_ * S_ / 256, 3), blk512, 0, stream>>>(
      QtKt, BSE, WQKt, (long)E_ * E_, E_, E_,
      nullptr, nullptr, 0, nullptr, 1.f, E_, nullptr, 0,
      nullptr, qkb, E_, BSE, nullptr, nullptr, 0, 0,
      /*capZ=*/2, /*capM=*/B_ * SVP_);

  // ---- qkT = [q^T ; k^T] per batch [2E,S]; fused colsum(k) -> ck ----
  transp2_bf16_k<<<dim3(E_ / 32, S_ / 32, 2 * B_), blk32x8, 0, stream>>>(
      qkb, BSE, E_, (long)S_ * E_, qkT, (long)E_ * S_, S_, (long)2 * E_ * S_, ck);

  // ---- logits = q k^T / 32 -> fb (bf16); softmax reads fb, writes Fout + fb ----
  gemm256_k<<<dim3(S_ / 256, S_ / 256, B_), blk512, 0, stream>>>(
      qb, (long)S_ * E_, kb, (long)S_ * E_, S_, E_,
      nullptr, nullptr, 0, nullptr, 1.f / 32.f, S_, nullptr, 0,
      nullptr, fb, S_, (long)S_ * S_, nullptr, nullptr, 0, 0,
      9999, 0);
  softmax_row_k<<<dim3(S_, B_), blk256, 0, stream>>>(fb, Fout);

  // ---- vq = q v^T/32 ; vkNeg = -k v^T/32 -> vqkf [b][2S][64] (one dispatch) ----
  gemm_vqk_k<<<dim3(1, S_ / 64, 2 * B_), blk256, 0, stream>>>(qkb, vb, vqkf);

  // ---- q2|k2 = [f@q + vq@Wvq | ck - (f@k - vk@Wvk)]  (one dispatch) ----
  gemm256_k<<<dim3(2 * E_ / 256, S_ / 256, B_), blk512, 0, stream>>>(
      fb, (long)S_ * S_, qkT, (long)2 * E_ * S_, 2 * E_, S_,
      vqkf, vqkf + (long)S_ * SVP_, (long)2 * S_ * SVP_, Wv2T,
      1.f, E_, ck, E_,
      nullptr, q2k2, 2 * E_, (long)S_ * 2 * E_,
      nullptr, q2k2 + E_, 2 * E_, (long)S_ * 2 * E_,
      9999, 0);

  // ---- q2k2T = [q2^T ; k2^T]; fused colsum(k2) -> ck2 ----
  transp2_bf16_k<<<dim3(E_ / 32, S_ / 32, 2 * B_), blk32x8, 0, stream>>>(
      q2k2, E_, 2 * E_, (long)S_ * 2 * E_, q2k2T, (long)E_ * S_, S_,
      (long)2 * E_ * S_, ck2);

  // ---- Q_out = f@q2 ; K_out = ck2 - f@k2  (one dispatch) ----
  gemm256_k<<<dim3(2 * E_ / 256, S_ / 256, B_), blk512, 0, stream>>>(
      fb, (long)S_ * S_, q2k2T, (long)2 * E_ * S_, 2 * E_, S_,
      nullptr, nullptr, 0, nullptr,
      1.f, E_, ck2, E_,
      Qout, nullptr, E_, (long)S_ * E_,
      Kout, nullptr, E_, (long)S_ * E_,
      9999, 0);
}

// Round 12
// 570.796 us; speedup vs baseline: 1.0163x; 1.0036x over previous
//
#include <hip/hip_runtime.h>
#include <cstdint>
#include <cstddef>

typedef __bf16 bf16_t;
typedef __bf16 bf16x4 __attribute__((ext_vector_type(4)));
typedef __bf16 bf16x8 __attribute__((ext_vector_type(8)));
typedef float floatx4 __attribute__((ext_vector_type(4)));

#define B_ 4
#define S_ 2048
#define E_ 1024
#define SV_ 50
#define SVP_ 64
#define BSE_ ((long)B_ * S_ * E_)

__device__ __forceinline__ void async_copy16(const bf16_t* g, bf16_t* l) {
  __builtin_amdgcn_global_load_lds(
      (const __attribute__((address_space(1))) void*)g,
      (__attribute__((address_space(3))) void*)l, 16, 0, 0);
}

__device__ __forceinline__ void vm_wait(int n) {
  if (n == 0)
    asm volatile("s_waitcnt vmcnt(0)" ::: "memory");
  else if (n == 2)
    asm volatile("s_waitcnt vmcnt(2)" ::: "memory");
  else if (n == 8)
    asm volatile("s_waitcnt vmcnt(8)" ::: "memory");
  else
    asm volatile("s_waitcnt vmcnt(10)" ::: "memory");
}

// ---------------- tanh of Q and K (concat), float4 vectorized ----------------
__global__ __launch_bounds__(256) void tanh2_k(const float* __restrict__ Q,
                                               const float* __restrict__ Kin,
                                               bf16_t* __restrict__ out) {
  long i4 = ((long)blockIdx.x * 256 + threadIdx.x) * 4;
  const long n = (long)B_ * S_ * E_;
  const float* src = (i4 < n) ? (Q + i4) : (Kin + (i4 - n));
  float4 x = *(const float4*)src;
  bf16x4 o;
  o[0] = (bf16_t)tanhf(x.x);
  o[1] = (bf16_t)tanhf(x.y);
  o[2] = (bf16_t)tanhf(x.z);
  o[3] = (bf16_t)tanhf(x.w);
  *(bf16x4*)&out[i4] = o;
}

// V [B,50,1024] -> tanh, padded to [B,64,1024] with zero rows
__global__ __launch_bounds__(256) void tanh_vpad_k(const float* __restrict__ V,
                                                   bf16_t* __restrict__ out) {
  int i = blockIdx.x * 256 + threadIdx.x;  // covers B*64*1024
  int e = i & 1023, r = (i >> 10) & 63, b = i >> 16;
  float v = 0.f;
  if (r < SV_) v = tanhf(V[((long)(b * SV_ + r) << 10) + e]);
  out[i] = (bf16_t)v;
}

// ------- W [K,N] fp32 -> Wt [N,Kp] bf16 (zero-pad k>=K); 3-way z select -------
__global__ __launch_bounds__(256) void transp_cast3_k(const float* __restrict__ W0,
                                                      const float* __restrict__ W1,
                                                      const float* __restrict__ W2,
                                                      bf16_t* __restrict__ out,
                                                      int K, int N, int Kp) {
  __shared__ float tile[32][33];
  const float* W = (blockIdx.z == 0) ? W0 : (blockIdx.z == 1) ? W1 : W2;
  bf16_t* o = out + (long)blockIdx.z * N * Kp;
  int k0 = blockIdx.y * 32, n0 = blockIdx.x * 32;
  int tx = threadIdx.x, ty = threadIdx.y;  // block (32,8)
#pragma unroll
  for (int s2 = 0; s2 < 4; ++s2) {
    int kk = ty + s2 * 8;
    float v = 0.f;
    if (k0 + kk < K && n0 + tx < N) v = W[(long)(k0 + kk) * N + n0 + tx];
    tile[kk][tx] = v;
  }
  __syncthreads();
#pragma unroll
  for (int s2 = 0; s2 < 4; ++s2) {
    int nn = ty + s2 * 8;
    if (n0 + nn < N && k0 + tx < Kp)
      o[(long)(n0 + nn) * Kp + k0 + tx] = (bf16_t)tile[tx][nn];
  }
}

// ------ strided bf16 transpose, dual-source via z: out[c][r] = in[r][c] ------
// If csum != null: for half==1 blocks, also accumulate column sums of the input
// into csum[bz*E_ + col] via one atomicAdd per column per block.
__global__ __launch_bounds__(256) void transp2_bf16_k(const bf16_t* __restrict__ in,
                                                      long selIn, long inRow,
                                                      long inBatch,
                                                      bf16_t* __restrict__ out,
                                                      long selOut, long outRow,
                                                      long outBatch,
                                                      float* __restrict__ csum) {
  __shared__ bf16_t tile[32][33];
  __shared__ float cs[8][32];
  int r0 = blockIdx.y * 32, c0 = blockIdx.x * 32;
  int tx = threadIdx.x, ty = threadIdx.y;  // block (32,8)
  int half = blockIdx.z & 1, bz = blockIdx.z >> 1;
  long ib = (long)bz * inBatch + (long)half * selIn;
  long ob = (long)bz * outBatch + (long)half * selOut;
  float ps = 0.f;
#pragma unroll
  for (int s2 = 0; s2 < 4; ++s2) {
    bf16_t v = in[ib + (long)(r0 + ty + s2 * 8) * inRow + c0 + tx];
    tile[ty + s2 * 8][tx] = v;
    ps += (float)v;
  }
  cs[ty][tx] = ps;
  __syncthreads();
#pragma unroll
  for (int s2 = 0; s2 < 4; ++s2)
    out[ob + (long)(c0 + ty + s2 * 8) * outRow + r0 + tx] = tile[tx][ty + s2 * 8];
  if (csum && half == 1 && ty == 0) {
    float s = 0.f;
#pragma unroll
    for (int c = 0; c < 8; ++c) s += cs[c][tx];
    atomicAdd(&csum[(long)bz * E_ + c0 + tx], s);
  }
}

// ------- row softmax: read bf16 logits from fb, write fp32 f + bf16 fb -------
__global__ __launch_bounds__(256) void softmax_row_k(bf16_t* __restrict__ fb,
                                                     float* __restrict__ Fout) {
  long off = ((long)blockIdx.y * S_ + blockIdx.x) * S_;
  int t = threadIdx.x;
  bf16x8 xb = *(const bf16x8*)&fb[off + 8 * t];
  float x[8];
#pragma unroll
  for (int i = 0; i < 8; ++i) x[i] = (float)xb[i];
  float mx = fmaxf(fmaxf(fmaxf(x[0], x[1]), fmaxf(x[2], x[3])),
                   fmaxf(fmaxf(x[4], x[5]), fmaxf(x[6], x[7])));
#pragma unroll
  for (int s = 32; s >= 1; s >>= 1) mx = fmaxf(mx, __shfl_xor(mx, s));
  __shared__ float red[4];
  int wv = t >> 6;
  if ((t & 63) == 0) red[wv] = mx;
  __syncthreads();
  mx = fmaxf(fmaxf(red[0], red[1]), fmaxf(red[2], red[3]));
  float e[8];
  float sum = 0.f;
#pragma unroll
  for (int i = 0; i < 8; ++i) {
    e[i] = __expf(x[i] - mx);
    sum += e[i];
  }
#pragma unroll
  for (int s = 32; s >= 1; s >>= 1) sum += __shfl_xor(sum, s);
  __shared__ float red2[4];
  if ((t & 63) == 0) red2[wv] = sum;
  __syncthreads();
  float inv = 1.0f / ((red2[0] + red2[1]) + (red2[2] + red2[3]));
  bf16x8 ob;
#pragma unroll
  for (int i = 0; i < 8; ++i) {
    e[i] *= inv;
    ob[i] = (bf16_t)e[i];
  }
  *(float4*)&Fout[off + 8 * t] = make_float4(e[0], e[1], e[2], e[3]);
  *(float4*)&Fout[off + 8 * t + 4] = make_float4(e[4], e[5], e[6], e[7]);
  *(bf16x8*)&fb[off + 8 * t] = ob;
}

// ---- fused vq/vk small NT GEMM (64x64 tile): grid (1, S/64, 8) ----
// z = sel*4 + b; sel 0: vq = q v^T/32; sel 1: vkNeg = -k v^T/32
__global__ __launch_bounds__(256) void gemm_vqk_k(const bf16_t* __restrict__ qkb,
                                                  const bf16_t* __restrict__ vb,
                                                  bf16_t* __restrict__ vqkf) {
  __shared__ __align__(16) bf16_t As[64 * 64];
  __shared__ __align__(16) bf16_t Bs[64 * 64];
  const int zz = blockIdx.z;
  const int sel = zz >> 2;
  const int b = zz & 3;
  const bf16_t* Ab = qkb + (long)sel * BSE_ + (long)b * S_ * E_;
  const bf16_t* Bb = vb + (long)b * SVP_ * E_;
  bf16_t* outB = vqkf + ((long)b * 2 + sel) * ((long)S_ * SVP_);
  const int t = threadIdx.x;
  const int lane = t & 63;
  const int wave = t >> 6;
  const int wm = (wave & 1) * 32;
  const int wn = (wave >> 1) * 32;
  const long rowBase = (long)blockIdx.y * 64;

  floatx4 acc[2][2];
#pragma unroll
  for (int i = 0; i < 2; ++i)
#pragma unroll
    for (int j = 0; j < 2; ++j) acc[i][j] = {0.f, 0.f, 0.f, 0.f};

  const int sr = t >> 3;
  const int sc = (t & 7) * 8;
  for (int k0 = 0; k0 < E_; k0 += 64) {
#pragma unroll
    for (int p = 0; p < 2; ++p) {
      int r = p * 32 + sr;
      *(uint4*)&As[r * 64 + sc] = *(const uint4*)&Ab[(rowBase + r) * E_ + k0 + sc];
      *(uint4*)&Bs[r * 64 + sc] = *(const uint4*)&Bb[(long)r * E_ + k0 + sc];
    }
    __syncthreads();
#pragma unroll
    for (int ks = 0; ks < 64; ks += 32) {
      const int fr = lane & 15;
      const int fk = ks + ((lane >> 4) << 3);
      bf16x8 a0 = *(const bf16x8*)&As[(wm + fr) * 64 + fk];
      bf16x8 a1 = *(const bf16x8*)&As[(wm + 16 + fr) * 64 + fk];
      bf16x8 b0 = *(const bf16x8*)&Bs[(wn + fr) * 64 + fk];
      bf16x8 b1 = *(const bf16x8*)&Bs[(wn + 16 + fr) * 64 + fk];
      acc[0][0] = __builtin_amdgcn_mfma_f32_16x16x32_bf16(a0, b0, acc[0][0], 0, 0, 0);
      acc[0][1] = __builtin_amdgcn_mfma_f32_16x16x32_bf16(a0, b1, acc[0][1], 0, 0, 0);
      acc[1][0] = __builtin_amdgcn_mfma_f32_16x16x32_bf16(a1, b0, acc[1][0], 0, 0, 0);
      acc[1][1] = __builtin_amdgcn_mfma_f32_16x16x32_bf16(a1, b1, acc[1][1], 0, 0, 0);
    }
    __syncthreads();
  }

  const int cr = lane & 15;
  const int rq = (lane >> 4) * 4;
  const float alpha = sel ? -1.f / 32.f : 1.f / 32.f;
#pragma unroll
  for (int i = 0; i < 2; ++i)
#pragma unroll
    for (int j = 0; j < 2; ++j)
#pragma unroll
      for (int r = 0; r < 4; ++r) {
        long row = rowBase + wm + i * 16 + rq + r;
        int col = wn + j * 16 + cr;
        outB[row * SVP_ + col] = (bf16_t)(alpha * acc[i][j][r]);
      }
}

// ===== 256x256 NT GEMM, 512 thr / 8 waves, BK=64, 4-phase + SPREAD staging =====
// Staging split into four 16 KB units matched to the read phases, issued ONE
// UNIT (2 loads) PER PHASE, running 4-6 phases ahead (fine interleave):
//   units: U0=SA_low (A h{0,2}, read P1)  U1=SB_a (B h{0,1})  U2=SB_b (B h{2,3})
//          U3=SA_high (A h{1,3}, read P3); B units read at P1+P2 (row blocks
//          wc*64+0..31 / +32..63 span both halves).
//   stage slots: t.P1 -> U2(t+1); t.P2 -> U3(t+1); t.P3 -> U0(t+2); t.P4 -> U1(t+2)
// vmcnt ledger (verified by walk-through): P1 vmcnt(8) retires {U0,U1,U2}(t);
// P3 vmcnt(10) retires U3(t). Tail: P1->2 at last tile; P3->8 at nt-2, ->0 at
// last tile (full drain before s_endpgm; no in-flight LDS-DMA at exit).
// Write-after-read safety: P3's same-buf U0 overwrite safe (P2 reads no SA_low;
// all P1 reads lgkm-complete before P2-start barrier); P4's U1 overwrite fenced
// by P3-start barrier (P3 reads only A); cross-buf stages at P1/P2 fenced by
// the previous tile's P4-start barrier.
// Swizzle: LDS(r,c) holds global(r, c ^ (r&7)) via pre-swizzled GLOBAL source;
// read chunk = hi ^ (fr&7). Conflict-free (R5-proven class).
__global__ __launch_bounds__(512, 2) void gemm256_k(
    const bf16_t* __restrict__ A1, long sA1,
    const bf16_t* __restrict__ B1, long sB1,
    int N, int K1,
    const bf16_t* __restrict__ A2q, const bf16_t* __restrict__ A2k, long sA2,
    const bf16_t* __restrict__ B2,
    float alpha, int negSplit, const float* __restrict__ colVec, long sV,
    float* __restrict__ outFa, bf16_t* __restrict__ outBa, int lda, long sOa,
    float* __restrict__ outFb, bf16_t* __restrict__ outBb, int ldb, long sOb,
    int capZ, int capM) {
  __shared__ __align__(16) bf16_t As[2 * 256 * 64];
  __shared__ __align__(16) bf16_t Bs[2 * 256 * 64];
  const int t = threadIdx.x;
  const int lane = t & 63;
  const int wave = t >> 6;  // 0..7
  const int wr = wave >> 2; // 0..1
  const int wc = wave & 3;  // 0..3
  const long b = blockIdx.z;
  const long rowBase = (long)blockIdx.y * 256;
  const long colBase = (long)blockIdx.x * 256;
  if ((int)b >= capZ && rowBase >= capM) return;
  const bf16_t* Ab = A1 + b * sA1;
  const bf16_t* Bb = B1 + b * sB1;

  floatx4 acc[8][4];
#pragma unroll
  for (int i = 0; i < 8; ++i)
#pragma unroll
    for (int j = 0; j < 4; ++j) acc[i][j] = {0.f, 0.f, 0.f, 0.f};

  // ---- staging geometry: thread covers row srow (+64*h), chunk pre-swizzled ----
  const int srow = t >> 3;                        // 0..63
  const int sch = (t & 7) ^ (srow & 7);           // inverse-swizzled 16B chunk
  const bf16_t* aG = Ab + (rowBase + srow) * (long)K1 + sch * 8;
  const bf16_t* bG = Bb + (colBase + srow) * (long)K1 + sch * 8;
  const bf16_t* A2 = A2q ? ((colBase >= negSplit) ? A2k : A2q) : nullptr;
  const bf16_t* a2G = A2 ? A2 + b * sA2 + (rowBase + srow) * 64 + sch * 8 : aG;
  const bf16_t* b2G = A2 ? B2 + (colBase + srow) * 64 + sch * 8 : bG;
  const int ldsW = (wave * 8) * 64;  // wave-uniform LDS base (elements)

  // ---- frag read offsets: row stride 64 elem, swizzled chunk ----
  const int fr = lane & 15;
  const int hi = lane >> 4;  // 0..3
  const int swz = (hi ^ (fr & 7)) * 8;
  int aoff[8], boff[4];
#pragma unroll
  for (int i = 0; i < 8; ++i) aoff[i] = (wr * 128 + i * 16 + fr) * 64 + swz;
#pragma unroll
  for (int j = 0; j < 4; ++j) boff[j] = (wc * 64 + j * 16 + fr) * 64 + swz;

  const int nK1 = K1 >> 6;
  const int nt = nK1 + (A2q ? 1 : 0);

  // unit u: 0=SA_low (A h{0,2})  1=SB_a (B h{0,1})  2=SB_b (B h{2,3})
  //         3=SA_high (A h{1,3}); 2 async_copy16 each.
  auto stageUnit = [&](int u, int buf, int kt) {
    const int bo = buf * (256 * 64);
    int h0, h1;
    bool isA;
    if (u == 0) { isA = true;  h0 = 0; h1 = 2; }
    else if (u == 1) { isA = false; h0 = 0; h1 = 1; }
    else if (u == 2) { isA = false; h0 = 2; h1 = 3; }
    else { isA = true;  h0 = 1; h1 = 3; }
    bf16_t* l = isA ? &As[bo + ldsW] : &Bs[bo + ldsW];
    if (kt < nK1) {
      const long k0 = (long)kt * 64;
      const bf16_t* g = isA ? aG : bG;
      async_copy16(g + (long)(h0 * 64) * K1 + k0, l + h0 * 64 * 64);
      async_copy16(g + (long)(h1 * 64) * K1 + k0, l + h1 * 64 * 64);
    } else {  // 64-wide K tail from A2/B2 (row stride 64)
      const bf16_t* g = isA ? a2G : b2G;
      async_copy16(g + h0 * 64 * 64, l + h0 * 64 * 64);
      async_copy16(g + h1 * 64 * 64, l + h1 * 64 * 64);
    }
  };

  // prologue: all 4 units of tile 0, then SA_low+SB_a of tile 1 (steady-state)
  stageUnit(0, 0, 0);
  stageUnit(1, 0, 0);
  stageUnit(2, 0, 0);
  stageUnit(3, 0, 0);
  if (nt > 1) {
    stageUnit(0, 1, 1);
    stageUnit(1, 1, 1);
  }

  for (int kt = 0; kt < nt; ++kt) {
    const int bo = (kt & 1) * (256 * 64);
    const int v1 = (kt + 1 < nt) ? 8 : 2;
    const int v3 = (kt + 2 < nt) ? 10 : ((kt + 1 < nt) ? 8 : 0);
    bf16x8 a0l[4], a0h[4], a1l[4], a1h[4], b0l[2], b0h[2], b1l[2], b1h[2];

    // ---- P1: stage SB_b(t+1); retire SA_low+SB of tile t; quadrant (i0-3,j0-1)
    if (kt + 1 < nt) stageUnit(2, (kt + 1) & 1, kt + 1);
    vm_wait(v1);
    __builtin_amdgcn_s_barrier();
    __builtin_amdgcn_sched_barrier(0);
#pragma unroll
    for (int i = 0; i < 4; ++i) {
      a0l[i] = *(const bf16x8*)&As[bo + aoff[i]];
      a0h[i] = *(const bf16x8*)&As[bo + (aoff[i] ^ 32)];
    }
#pragma unroll
    for (int j = 0; j < 2; ++j) {
      b0l[j] = *(const bf16x8*)&Bs[bo + boff[j]];
      b0h[j] = *(const bf16x8*)&Bs[bo + (boff[j] ^ 32)];
    }
    __builtin_amdgcn_s_setprio(1);
#pragma unroll
    for (int i = 0; i < 4; ++i)
#pragma unroll
      for (int j = 0; j < 2; ++j) {
        acc[i][j] = __builtin_amdgcn_mfma_f32_16x16x32_bf16(a0l[i], b0l[j], acc[i][j], 0, 0, 0);
        acc[i][j] = __builtin_amdgcn_mfma_f32_16x16x32_bf16(a0h[i], b0h[j], acc[i][j], 0, 0, 0);
      }
    __builtin_amdgcn_s_setprio(0);
    __builtin_amdgcn_sched_barrier(0);

    // ---- P2: stage SA_high(t+1); quadrant (i0-3, j2-3), a0 held
    if (kt + 1 < nt) stageUnit(3, (kt + 1) & 1, kt + 1);
    __builtin_amdgcn_s_barrier();
    __builtin_amdgcn_sched_barrier(0);
#pragma unroll
    for (int j = 0; j < 2; ++j) {
      b1l[j] = *(const bf16x8*)&Bs[bo + boff[j + 2]];
      b1h[j] = *(const bf16x8*)&Bs[bo + (boff[j + 2] ^ 32)];
    }
    __builtin_amdgcn_s_setprio(1);
#pragma unroll
    for (int i = 0; i < 4; ++i)
#pragma unroll
      for (int j = 0; j < 2; ++j) {
        acc[i][j + 2] = __builtin_amdgcn_mfma_f32_16x16x32_bf16(a0l[i], b1l[j], acc[i][j + 2], 0, 0, 0);
        acc[i][j + 2] = __builtin_amdgcn_mfma_f32_16x16x32_bf16(a0h[i], b1h[j], acc[i][j + 2], 0, 0, 0);
      }
    __builtin_amdgcn_s_setprio(0);
    __builtin_amdgcn_sched_barrier(0);

    // ---- P3: stage SA_low(t+2); retire SA_high(t); quadrant (i4-7, j2-3)
    if (kt + 2 < nt) stageUnit(0, (kt + 2) & 1, kt + 2);
    vm_wait(v3);
    __builtin_amdgcn_s_barrier();
    __builtin_amdgcn_sched_barrier(0);
#pragma unroll
    for (int i = 0; i < 4; ++i) {
      a1l[i] = *(const bf16x8*)&As[bo + aoff[i + 4]];
      a1h[i] = *(const bf16x8*)&As[bo + (aoff[i + 4] ^ 32)];
    }
    __builtin_amdgcn_s_setprio(1);
#pragma unroll
    for (int i = 0; i < 4; ++i)
#pragma unroll
      for (int j = 0; j < 2; ++j) {
        acc[i + 4][j + 2] = __builtin_amdgcn_mfma_f32_16x16x32_bf16(a1l[i], b1l[j], acc[i + 4][j + 2], 0, 0, 0);
        acc[i + 4][j + 2] = __builtin_amdgcn_mfma_f32_16x16x32_bf16(a1h[i], b1h[j], acc[i + 4][j + 2], 0, 0, 0);
      }
    __builtin_amdgcn_s_setprio(0);
    __builtin_amdgcn_sched_barrier(0);

    // ---- P4: stage SB_a(t+2); quadrant (i4-7, j0-1), a1+b0 held
    if (kt + 2 < nt) stageUnit(1, (kt + 2) & 1, kt + 2);
    __builtin_amdgcn_s_barrier();
    __builtin_amdgcn_sched_barrier(0);
    __builtin_amdgcn_s_setprio(1);
#pragma unroll
    for (int i = 0; i < 4; ++i)
#pragma unroll
      for (int j = 0; j < 2; ++j) {
        acc[i + 4][j] = __builtin_amdgcn_mfma_f32_16x16x32_bf16(a1l[i], b0l[j], acc[i + 4][j], 0, 0, 0);
        acc[i + 4][j] = __builtin_amdgcn_mfma_f32_16x16x32_bf16(a1h[i], b0h[j], acc[i + 4][j], 0, 0, 0);
      }
    __builtin_amdgcn_s_setprio(0);
    __builtin_amdgcn_sched_barrier(0);
  }

  // ---- epilogue ----
  const int cr = lane & 15;
  const int rq = hi * 4;
  const bool neg = (colBase >= negSplit);
  const float* cv = colVec ? (colVec + b * sV + (neg ? colBase - negSplit : colBase))
                           : nullptr;
  float* oF = neg ? outFb : outFa;
  bf16_t* oB = neg ? outBb : outBa;
  const int ld = neg ? ldb : lda;
  const long sO = neg ? sOb : sOa;
  const long cb0 = neg ? (long)(colBase - negSplit) : colBase;
#pragma unroll
  for (int i = 0; i < 8; ++i)
#pragma unroll
    for (int j = 0; j < 4; ++j)
#pragma unroll
      for (int r = 0; r < 4; ++r) {
        long row = rowBase + wr * 128 + i * 16 + rq + r;
        int c = wc * 64 + j * 16 + cr;
        float v = alpha * acc[i][j][r];
        if (neg) v = cv[c] - v;
        long o = b * sO + row * (long)ld + cb0 + c;
        if (oF) oF[o] = v;
        if (oB) oB[o] = (bf16_t)v;
      }
}

extern "C" void kernel_launch(void* const* d_in, const int* in_sizes, int n_in,
                              void* d_out, int out_size, void* d_ws, size_t ws_size,
                              hipStream_t stream) {
  const float* Q = (const float*)d_in[0];
  const float* Kin = (const float*)d_in[1];
  const float* V = (const float*)d_in[2];
  const float* W_Q = (const float*)d_in[3];
  const float* W_K = (const float*)d_in[4];
  const float* W_v = (const float*)d_in[5];
  const float* W_vq = (const float*)d_in[6];
  const float* W_vk = (const float*)d_in[7];

  float* Qout = (float*)d_out;              // [4,2048,1024]
  float* Kout = Qout + (long)B_ * S_ * E_;  // [4,2048,1024]
  float* Fout = Kout + (long)B_ * S_ * E_;  // [4,2048,2048] fp32 f

  char* w = (char*)d_ws;
  auto alloc = [&](size_t bytes) {
    char* p = w;
    w += (bytes + 255) & ~(size_t)255;
    return p;
  };
  const long BSE = BSE_;
  bf16_t* WQKt = (bf16_t*)alloc((size_t)2 * 2 * E_ * E_);   // [WQt | WKt], each [E,E]
  bf16_t* WVt = (bf16_t*)alloc((size_t)2 * E_ * E_);        // [E,E] == WQKt + 2*E*E
  bf16_t* Wv2T = (bf16_t*)alloc((size_t)2 * 2 * E_ * SVP_); // [2E,64]: Wvq^T ; Wvk^T
  bf16_t* QtKt = (bf16_t*)alloc((size_t)2 * 2 * BSE);       // tanh(Q);tanh(K) [16384,E]
  bf16_t* Vt = (bf16_t*)alloc((size_t)2 * B_ * SVP_ * E_);  // [256,E] == QtKt + 2*BSE
  bf16_t* qkb = (bf16_t*)alloc((size_t)2 * 2 * BSE);        // q ; k   [16384,E]
  bf16_t* vb = (bf16_t*)alloc((size_t)2 * B_ * SVP_ * E_);  // v [256,E] == qkb + 2*BSE
  bf16_t* qkT = (bf16_t*)alloc((size_t)2 * (long)B_ * 2 * E_ * S_);  // [b][2E][S]
  bf16_t* fb = (bf16_t*)alloc((size_t)2 * (long)B_ * S_ * S_);       // logits -> f bf16
  bf16_t* vqkf = (bf16_t*)alloc((size_t)2 * (long)B_ * 2 * S_ * SVP_); // [b][2S][64]
  bf16_t* q2k2 = (bf16_t*)alloc((size_t)2 * (long)B_ * S_ * 2 * E_);   // [b][S][2E]
  bf16_t* q2k2T = (bf16_t*)alloc((size_t)2 * (long)B_ * 2 * E_ * S_);  // [b][2E][S]
  float* ck = (float*)alloc((size_t)4 * B_ * E_);
  float* ck2 = (float*)alloc((size_t)4 * B_ * E_);

  bf16_t* qb = qkb;
  bf16_t* kb = qkb + BSE;

  dim3 blk256(256);
  dim3 blk512(512);
  dim3 blk32x8(32, 8);

  // ---- zero colsum accumulators (ck | ck2 contiguous) ----
  hipMemsetAsync(ck, 0, (size_t)2 * 4 * B_ * E_, stream);

  // ---- weight prep (merged: 2 dispatches) ----
  transp_cast3_k<<<dim3(32, 32, 3), blk32x8, 0, stream>>>(W_Q, W_K, W_v, WQKt,
                                                          E_, E_, E_);
  transp_cast3_k<<<dim3(32, 2, 2), blk32x8, 0, stream>>>(W_vq, W_vk, W_vq, Wv2T,
                                                         SV_, E_, SVP_);

  // ---- tanh + cast inputs ----
  tanh2_k<<<dim3((unsigned)(2 * BSE / 1024)), blk256, 0, stream>>>(Q, Kin, QtKt);
  tanh_vpad_k<<<dim3(B_ * SVP_ * E_ / 256), blk256, 0, stream>>>(V, Vt);

  // ---- Q,K,V projections fused via z (0: Qt@WQt, 1: Kt@WKt, 2: Vt@WVt) ----
  gemm256_k<<<dim3(E_ / 256, B_ * S_ / 256, 3), blk512, 0, stream>>>(
      QtKt, BSE, WQKt, (long)E_ * E_, E_, E_,
      nullptr, nullptr, 0, nullptr, 1.f, E_, nullptr, 0,
      nullptr, qkb, E_, BSE, nullptr, nullptr, 0, 0,
      /*capZ=*/2, /*capM=*/B_ * SVP_);

  // ---- qkT = [q^T ; k^T] per batch [2E,S]; fused colsum(k) -> ck ----
  transp2_bf16_k<<<dim3(E_ / 32, S_ / 32, 2 * B_), blk32x8, 0, stream>>>(
      qkb, BSE, E_, (long)S_ * E_, qkT, (long)E_ * S_, S_, (long)2 * E_ * S_, ck);

  // ---- logits = q k^T / 32 -> fb (bf16); softmax reads fb, writes Fout + fb ----
  gemm256_k<<<dim3(S_ / 256, S_ / 256, B_), blk512, 0, stream>>>(
      qb, (long)S_ * E_, kb, (long)S_ * E_, S_, E_,
      nullptr, nullptr, 0, nullptr, 1.f / 32.f, S_, nullptr, 0,
      nullptr, fb, S_, (long)S_ * S_, nullptr, nullptr, 0, 0,
      9999, 0);
  softmax_row_k<<<dim3(S_, B_), blk256, 0, stream>>>(fb, Fout);

  // ---- vq = q v^T/32 ; vkNeg = -k v^T/32 -> vqkf [b][2S][64] (one dispatch) ----
  gemm_vqk_k<<<dim3(1, S_ / 64, 2 * B_), blk256, 0, stream>>>(qkb, vb, vqkf);

  // ---- q2|k2 = [f@q + vq@Wvq | ck - (f@k - vk@Wvk)]  (one dispatch) ----
  gemm256_k<<<dim3(2 * E_ / 256, S_ / 256, B_), blk512, 0, stream>>>(
      fb, (long)S_ * S_, qkT, (long)2 * E_ * S_, 2 * E_, S_,
      vqkf, vqkf + (long)S_ * SVP_, (long)2 * S_ * SVP_, Wv2T,
      1.f, E_, ck, E_,
      nullptr, q2k2, 2 * E_, (long)S_ * 2 * E_,
      nullptr, q2k2 + E_, 2 * E_, (long)S_ * 2 * E_,
      9999, 0);

  // ---- q2k2T = [q2^T ; k2^T]; fused colsum(k2) -> ck2 ----
  transp2_bf16_k<<<dim3(E_ / 32, S_ / 32, 2 * B_), blk32x8, 0, stream>>>(
      q2k2, E_, 2 * E_, (long)S_ * 2 * E_, q2k2T, (long)E_ * S_, S_,
      (long)2 * E_ * S_, ck2);

  // ---- Q_out = f@q2 ; K_out = ck2 - f@k2  (one dispatch) ----
  gemm256_k<<<dim3(2 * E_ / 256, S_ / 256, B_), blk512, 0, stream>>>(
      fb, (long)S_ * S_, q2k2T, (long)2 * E_ * S_, 2 * E_, S_,
      nullptr, nullptr, 0, nullptr,
      1.f, E_, ck2, E_,
      Qout, nullptr, E_, (long)S_ * E_,
      Kout, nullptr, E_, (long)S_ * E_,
      9999, 0);
}